// Round 1
// baseline (205.810 us; speedup 1.0000x reference)
//
#include <hip/hip_runtime.h>
#include <hip/hip_bf16.h>

typedef __attribute__((ext_vector_type(8))) short short8;
typedef __attribute__((ext_vector_type(4))) short short4v;
typedef __attribute__((ext_vector_type(4))) float floatx4;
typedef __attribute__((ext_vector_type(2))) float floatx2;

#define MFMA16(a, b, c) __builtin_amdgcn_mfma_f32_16x16x32_bf16((a), (b), (c), 0, 0, 0)

#define SEQ 8192
#define SCALE_LOG2E 0.18033688011112042f  /* (1/sqrt(64)) * log2(e) */

__device__ __forceinline__ unsigned short f2bf(float f) {
    union { float f; unsigned u; } c; c.f = f;
    unsigned u = c.u;
    u += 0x7fffu + ((u >> 16) & 1u);   // round-to-nearest-even
    return (unsigned short)(u >> 16);
}
__device__ __forceinline__ float bf2f(unsigned short b) {
    union { unsigned u; float f; } c; c.u = ((unsigned)b) << 16;
    return c.f;
}

// ---------------- w_eff[d][j] = sum_h w_o[h*64+d][j] ----------------
__global__ void weff_kernel(const float* __restrict__ w_o, float* __restrict__ weff) {
    int idx = blockIdx.x * 256 + threadIdx.x;   // 64*512 total
    int d = idx >> 9, j = idx & 511;
    float s = 0.f;
#pragma unroll
    for (int h = 0; h < 8; ++h) s += w_o[((h * 64 + d) << 9) + j];
    weff[idx] = s;
}

// ---------------- flash attention (one head), hi/lo-split QK^T ----------------
// Grid: (SEQ/64, KSPLIT). Block: 256 (4 waves, each owns 16 q rows).
// Writes partial (acc, m, l) per kv-split; combine_kernel merges.
__global__ __launch_bounds__(256, 2) void flash_kernel(
        const float* __restrict__ qg, const float* __restrict__ kg_,
        const float* __restrict__ vg, float* __restrict__ pacc,
        float* __restrict__ pm, float* __restrict__ pl, int kvlen) {
    // +8 ushort padding per row (row = 144 B) -> conflict-free ds_read_b128
    __shared__ __align__(16) unsigned short Khi[64][72];
    __shared__ __align__(16) unsigned short Klo[64][72];
    __shared__ __align__(16) unsigned short Vt[64][72];   // V transposed: Vt[d][t]
    __shared__ __align__(16) unsigned short Pt[4][16][72]; // per-wave P tile

    const int tid  = threadIdx.x;
    const int lane = tid & 63;
    const int w    = tid >> 6;
    const int l15  = lane & 15;
    const int kgi  = lane >> 4;
    const int qbase = blockIdx.x * 64;
    const int split = blockIdx.y;
    const int kv0   = split * kvlen;

    // ---- Q fragments (scale folded in, hi/lo bf16 split), held in registers ----
    short8 qh[2], qlo[2];
    {
        const float* qp = qg + (size_t)(qbase + w * 16 + l15) * 64 + kgi * 8;
#pragma unroll
        for (int kc = 0; kc < 2; ++kc) {
            floatx4 a = *(const floatx4*)(qp + kc * 32);
            floatx4 b = *(const floatx4*)(qp + kc * 32 + 4);
            float x[8] = {a[0], a[1], a[2], a[3], b[0], b[1], b[2], b[3]};
            short8 h, lo;
#pragma unroll
            for (int j = 0; j < 8; ++j) {
                float xs = x[j] * SCALE_LOG2E;
                unsigned short hb = f2bf(xs);
                h[j]  = (short)hb;
                lo[j] = (short)f2bf(xs - bf2f(hb));
            }
            qh[kc] = h; qlo[kc] = lo;
        }
    }

    floatx4 acc[4];
#pragma unroll
    for (int i = 0; i < 4; ++i) acc[i] = (floatx4){0.f, 0.f, 0.f, 0.f};
    float m_r[4] = {-1e30f, -1e30f, -1e30f, -1e30f};
    float l_r[4] = {0.f, 0.f, 0.f, 0.f};

    const int ntiles = kvlen >> 6;
    for (int t = 0; t < ntiles; ++t) {
        const int kvb = kv0 + (t << 6);
        __syncthreads();   // previous tile's LDS reads done before overwrite

        // ---- stage K tile (64x64) as bf16 hi/lo ----
        {
            const int rr = tid >> 2, cc = tid & 3;
            const float* kp = kg_ + (size_t)(kvb + rr) * 64 + cc * 4;
#pragma unroll
            for (int i = 0; i < 4; ++i) {
                floatx4 f = *(const floatx4*)(kp + 16 * i);
                short4v h, lo;
#pragma unroll
                for (int j = 0; j < 4; ++j) {
                    unsigned short hb = f2bf(f[j]);
                    h[j]  = (short)hb;
                    lo[j] = (short)f2bf(f[j] - bf2f(hb));
                }
                *(short4v*)&Khi[rr][(cc + 4 * i) * 4] = h;
                *(short4v*)&Klo[rr][(cc + 4 * i) * 4] = lo;
            }
        }
        // ---- stage V tile transposed (Vt[d][t]), bf16 ----
        {
            const int pr = tid >> 3, c8 = tid & 7;
            const float* vp0 = vg + (size_t)(kvb + 2 * pr) * 64 + c8 * 8;
            floatx4 a0 = *(const floatx4*)(vp0);
            floatx4 a1 = *(const floatx4*)(vp0 + 4);
            floatx4 b0 = *(const floatx4*)(vp0 + 64);
            floatx4 b1 = *(const floatx4*)(vp0 + 68);
            float r0[8] = {a0[0],a0[1],a0[2],a0[3],a1[0],a1[1],a1[2],a1[3]};
            float r1[8] = {b0[0],b0[1],b0[2],b0[3],b1[0],b1[1],b1[2],b1[3]};
#pragma unroll
            for (int j = 0; j < 8; ++j) {
                unsigned u = (unsigned)f2bf(r0[j]) | ((unsigned)f2bf(r1[j]) << 16);
                *(unsigned*)&Vt[c8 * 8 + j][2 * pr] = u;
            }
        }
        __syncthreads();

        // ---- QK^T: S[16 q][64 t], split-precision (3 MFMAs per chunk) ----
        floatx4 s[4];
#pragma unroll
        for (int ct = 0; ct < 4; ++ct) {
            floatx4 a = (floatx4){0.f, 0.f, 0.f, 0.f};
#pragma unroll
            for (int kc = 0; kc < 2; ++kc) {
                const short8 kh = *(const short8*)&Khi[ct * 16 + l15][kc * 32 + kgi * 8];
                const short8 kl = *(const short8*)&Klo[ct * 16 + l15][kc * 32 + kgi * 8];
                a = MFMA16(qlo[kc], kh, a);
                a = MFMA16(qh[kc], kl, a);
                a = MFMA16(qh[kc], kh, a);
            }
            s[ct] = a;
        }

        // ---- online softmax (log2 domain); rows live in 16-lane groups ----
        float alpha[4];
#pragma unroll
        for (int r = 0; r < 4; ++r) {
            float tm = fmaxf(fmaxf(s[0][r], s[1][r]), fmaxf(s[2][r], s[3][r]));
#pragma unroll
            for (int msk = 1; msk < 16; msk <<= 1)
                tm = fmaxf(tm, __shfl_xor(tm, msk, 16));
            float nm = fmaxf(m_r[r], tm);
            alpha[r] = __builtin_amdgcn_exp2f(m_r[r] - nm);
            m_r[r] = nm;
            float ps = 0.f;
#pragma unroll
            for (int ct = 0; ct < 4; ++ct) {
                float p = __builtin_amdgcn_exp2f(s[ct][r] - nm);
                s[ct][r] = p;
                ps += p;
            }
#pragma unroll
            for (int msk = 1; msk < 16; msk <<= 1)
                ps += __shfl_xor(ps, msk, 16);
            l_r[r] = l_r[r] * alpha[r] + ps;
        }
#pragma unroll
        for (int dblk = 0; dblk < 4; ++dblk) {
            floatx4 a = acc[dblk];
            a[0] *= alpha[0]; a[1] *= alpha[1]; a[2] *= alpha[2]; a[3] *= alpha[3];
            acc[dblk] = a;
        }
        // ---- P -> LDS (bf16) for MFMA-A layout ----
#pragma unroll
        for (int ct = 0; ct < 4; ++ct)
#pragma unroll
            for (int r = 0; r < 4; ++r)
                Pt[w][kgi * 4 + r][ct * 16 + l15] = f2bf(s[ct][r]);
        __syncthreads();

        // ---- PV: acc += P(16x64) @ V(64x64) ----
#pragma unroll
        for (int kc2 = 0; kc2 < 2; ++kc2) {
            const short8 pa = *(const short8*)&Pt[w][l15][kc2 * 32 + kgi * 8];
#pragma unroll
            for (int dblk = 0; dblk < 4; ++dblk) {
                const short8 vb = *(const short8*)&Vt[dblk * 16 + l15][kc2 * 32 + kgi * 8];
                acc[dblk] = MFMA16(pa, vb, acc[dblk]);
            }
        }
    }

    // ---- epilogue: write partials ----
#pragma unroll
    for (int r = 0; r < 4; ++r) {
        const int qq = qbase + w * 16 + kgi * 4 + r;
        if (l15 == 0) {
            pm[(size_t)split * SEQ + qq] = m_r[r];
            pl[(size_t)split * SEQ + qq] = l_r[r];
        }
#pragma unroll
        for (int dblk = 0; dblk < 4; ++dblk)
            pacc[((size_t)split * SEQ + qq) * 64 + dblk * 16 + l15] = acc[dblk][r];
    }
}

// ---------------- combine kv-split partials -> head[8192][64] ----------------
__global__ void combine_kernel(const float* __restrict__ pacc, const float* __restrict__ pm,
                               const float* __restrict__ pl, float* __restrict__ head, int KS) {
    int idx = blockIdx.x * 256 + threadIdx.x;  // 8192*64
    int qq = idx >> 6, d = idx & 63;
    float M = -1e30f;
    for (int s2 = 0; s2 < KS; ++s2) M = fmaxf(M, pm[(size_t)s2 * SEQ + qq]);
    float L = 0.f, A = 0.f;
    for (int s2 = 0; s2 < KS; ++s2) {
        float wgt = __builtin_amdgcn_exp2f(pm[(size_t)s2 * SEQ + qq] - M);
        L += pl[(size_t)s2 * SEQ + qq] * wgt;
        A += pacc[((size_t)s2 * SEQ + qq) * 64 + d] * wgt;
    }
    head[idx] = A / L;
}

// ---------------- out = head[8192][64] @ w_eff[64][512] (fp32) ----------------
__global__ __launch_bounds__(256) void outproj_kernel(const float* __restrict__ head,
                                                      const float* __restrict__ weff,
                                                      float* __restrict__ out) {
    __shared__ float hlds[16][64];
    const int tid = threadIdx.x;
    const int s0 = blockIdx.x * 16;
    {
        int sl = tid >> 4, dc = (tid & 15) * 4;
        *(floatx4*)&hlds[sl][dc] = *(const floatx4*)&head[(size_t)(s0 + sl) * 64 + dc];
    }
    __syncthreads();
    const int j0 = tid * 2;
    float a0[16], a1[16];
#pragma unroll
    for (int s = 0; s < 16; ++s) { a0[s] = 0.f; a1[s] = 0.f; }
    for (int d4 = 0; d4 < 16; ++d4) {
        floatx2 wv[4];
#pragma unroll
        for (int dd = 0; dd < 4; ++dd)
            wv[dd] = *(const floatx2*)&weff[(size_t)(d4 * 4 + dd) * 512 + j0];
#pragma unroll
        for (int s = 0; s < 16; ++s) {
            floatx4 h = *(const floatx4*)&hlds[s][d4 * 4];
#pragma unroll
            for (int dd = 0; dd < 4; ++dd) {
                a0[s] += h[dd] * wv[dd][0];
                a1[s] += h[dd] * wv[dd][1];
            }
        }
    }
#pragma unroll
    for (int s = 0; s < 16; ++s) {
        floatx2 o = {a0[s], a1[s]};
        *(floatx2*)&out[(size_t)(s0 + s) * 512 + j0] = o;
    }
}

extern "C" void kernel_launch(void* const* d_in, const int* in_sizes, int n_in,
                              void* d_out, int out_size, void* d_ws, size_t ws_size,
                              hipStream_t stream) {
    const float* q   = (const float*)d_in[0];
    const float* k   = (const float*)d_in[1];
    const float* v   = (const float*)d_in[2];
    const float* w_o = (const float*)d_in[3];
    float* out = (float*)d_out;

    const size_t weff_sz = 64 * 512 * sizeof(float);
    const size_t head_sz = (size_t)SEQ * 64 * sizeof(float);
    auto need = [&](int ks) {
        return weff_sz + head_sz + (size_t)ks * SEQ * 64 * sizeof(float)
               + 2 * (size_t)ks * SEQ * sizeof(float);
    };
    const int KS = (ws_size >= need(4)) ? 4 : 1;

    char* p = (char*)d_ws;
    float* weff = (float*)p;  p += weff_sz;
    float* pacc = (float*)p;  p += (size_t)KS * SEQ * 64 * sizeof(float);
    float* pm   = (float*)p;  p += (size_t)KS * SEQ * sizeof(float);
    float* pl   = (float*)p;  p += (size_t)KS * SEQ * sizeof(float);
    float* head = (float*)p;

    weff_kernel<<<dim3(128), dim3(256), 0, stream>>>(w_o, weff);
    flash_kernel<<<dim3(SEQ / 64, KS), dim3(256), 0, stream>>>(q, k, v, pacc, pm, pl, SEQ / KS);
    combine_kernel<<<dim3((SEQ * 64) / 256), dim3(256), 0, stream>>>(pacc, pm, pl, head, KS);
    outproj_kernel<<<dim3(SEQ / 16), dim3(256), 0, stream>>>(head, weff, out);
}

// Round 3
// 143.230 us; speedup vs baseline: 1.4369x; 1.4369x over previous
//
#include <hip/hip_runtime.h>
#include <hip/hip_bf16.h>

typedef __attribute__((ext_vector_type(8))) short short8;
typedef __attribute__((ext_vector_type(4))) float floatx4;
typedef __attribute__((ext_vector_type(2))) float floatx2;
typedef __attribute__((ext_vector_type(2))) unsigned int uint2v;

#define MFMA16(a, b, c) __builtin_amdgcn_mfma_f32_16x16x32_bf16((a), (b), (c), 0, 0, 0)

#define SEQ 8192
#define SCALE_LOG2E 0.18033688011112042f  /* (1/sqrt(64)) * log2(e) */

__device__ __forceinline__ unsigned short f2bf(float f) {
    union { float f; unsigned u; } c; c.f = f;
    unsigned u = c.u;
    u += 0x7fffu + ((u >> 16) & 1u);   // round-to-nearest-even
    return (unsigned short)(u >> 16);
}
__device__ __forceinline__ float bf2f(unsigned short b) {
    union { unsigned u; float f; } c; c.u = ((unsigned)b) << 16;
    return c.f;
}
__device__ __forceinline__ unsigned pkbf(float a, float b) {
    return (unsigned)f2bf(a) | ((unsigned)f2bf(b) << 16);
}
__device__ __forceinline__ void gload16(const void* gptr, void* lptr) {
    __builtin_amdgcn_global_load_lds(
        (const __attribute__((address_space(1))) void*)gptr,
        (__attribute__((address_space(3))) void*)lptr, 16, 0, 0);
}
__device__ __forceinline__ void block_barrier() {
    asm volatile("" ::: "memory");
    __builtin_amdgcn_s_barrier();
    asm volatile("" ::: "memory");
}

// ---------------- w_eff[d][j] = sum_h w_o[h*64+d][j] ----------------
__global__ void weff_kernel(const float* __restrict__ w_o, float* __restrict__ weff) {
    int idx = blockIdx.x * 256 + threadIdx.x;   // 64*512 total
    int d = idx >> 9, j = idx & 511;
    float s = 0.f;
#pragma unroll
    for (int h = 0; h < 8; ++h) s += w_o[((h * 64 + d) << 9) + j];
    weff[idx] = s;
}

// ---------------- K -> bf16 hi/lo, row-major [SEQ][64] ----------------
__global__ void khilo_kernel(const float* __restrict__ kg, unsigned short* __restrict__ khi,
                             unsigned short* __restrict__ klo) {
    int idx = blockIdx.x * 256 + threadIdx.x;   // SEQ*64/8 threads
    int e = idx * 8;
    floatx4 a = *(const floatx4*)(kg + e);
    floatx4 b = *(const floatx4*)(kg + e + 4);
    float x[8] = {a[0], a[1], a[2], a[3], b[0], b[1], b[2], b[3]};
    short8 h, lo;
#pragma unroll
    for (int j = 0; j < 8; ++j) {
        unsigned short hb = f2bf(x[j]);
        h[j]  = (short)hb;
        lo[j] = (short)f2bf(x[j] - bf2f(hb));
    }
    *(short8*)(khi + e) = h;
    *(short8*)(klo + e) = lo;
}

// ---------------- V [SEQ][64] f32 -> Vt [64][SEQ] bf16 ----------------
__global__ void vtrans_kernel(const float* __restrict__ vg, unsigned short* __restrict__ vt) {
    __shared__ unsigned short T[64][72];
    const int tid = threadIdx.x;
    const int t0 = blockIdx.x * 64;
    {
        int r = tid >> 2, cs = (tid & 3) * 16;
        const float* vp = vg + (size_t)(t0 + r) * 64 + cs;
        short8 h0, h1;
#pragma unroll
        for (int j = 0; j < 8; ++j) { h0[j] = (short)f2bf(vp[j]); h1[j] = (short)f2bf(vp[8 + j]); }
        *(short8*)&T[r][cs] = h0;
        *(short8*)&T[r][cs + 8] = h1;
    }
    __syncthreads();
    {
        int d = tid >> 2, ts = (tid & 3) * 16;
        short8 o0, o1;
#pragma unroll
        for (int j = 0; j < 8; ++j) { o0[j] = (short)T[ts + j][d]; o1[j] = (short)T[ts + 8 + j][d]; }
        *(short8*)(vt + (size_t)d * SEQ + t0 + ts) = o0;
        *(short8*)(vt + (size_t)d * SEQ + t0 + ts + 8) = o1;
    }
}

// ---------------- flash attention, swapped-operand, gload_lds + dbuf ----------------
// Grid: (SEQ/64, KS). Block 256 = 4 waves; wave w owns q columns qbase+w*16+l15.
// LDS tile buffer (per buf): Khi[64][64] | Klo[64][64] | Vt[64][64] bf16, 16B-granule
// XOR-swizzled (granule g stored at g ^ (row&7)); filled linearly by global_load_lds
// with inverse-swizzled SOURCE addresses (LDS stays linear).
__global__ __launch_bounds__(256, 2) void flash_kernel(
        const float* __restrict__ qg, const unsigned short* __restrict__ khi,
        const unsigned short* __restrict__ klo, const unsigned short* __restrict__ vt,
        float* __restrict__ pacc, float* __restrict__ pm, float* __restrict__ pl,
        int kvlen) {
    __shared__ __align__(16) char lds[2][24576];
    __shared__ __align__(16) unsigned short PT[4][16][72];   // per-wave P^T staging

    const int tid  = threadIdx.x;
    const int lane = tid & 63;
    const int w    = tid >> 6;
    const int l15  = lane & 15;
    const int kgi  = lane >> 4;
    const int qbase = blockIdx.x * 64;
    const int split = blockIdx.y;
    const int kv0   = split * kvlen;
    const int nt    = kvlen >> 6;

    // staging geometry: thread covers rows r0 (h=0) / r0+32 (h=1), source granule g8
    const int r0 = tid >> 3;                               // 0..31
    const int g8 = (((tid & 7) ^ (r0 & 7)) << 3);          // swizzled granule * 8 elems

    auto STAGE = [&](int bsel, int kvb) {
        char* b = lds[bsel];
        const size_t ko = (size_t)(kvb + r0) * 64 + g8;
        const size_t vo = (size_t)r0 * SEQ + kvb + g8;
        gload16(khi + ko,                  b + tid * 16);
        gload16(khi + ko + 32 * 64,        b + 4096  + tid * 16);
        gload16(klo + ko,                  b + 8192  + tid * 16);
        gload16(klo + ko + 32 * 64,        b + 12288 + tid * 16);
        gload16(vt + vo,                   b + 16384 + tid * 16);
        gload16(vt + vo + (size_t)32 * SEQ, b + 20480 + tid * 16);
    };

    // ---- issue Q loads, then prefetch tiles 0,1, then convert Q ----
    const float* qp = qg + (size_t)(qbase + w * 16 + l15) * 64 + kgi * 8;
    floatx4 q0 = *(const floatx4*)(qp);
    floatx4 q1 = *(const floatx4*)(qp + 4);
    floatx4 q2 = *(const floatx4*)(qp + 32);
    floatx4 q3 = *(const floatx4*)(qp + 36);

    STAGE(0, kv0);
    if (nt > 1) STAGE(1, kv0 + 64);

    short8 qh[2], ql[2];
    {
        float x[2][8] = {{q0[0], q0[1], q0[2], q0[3], q1[0], q1[1], q1[2], q1[3]},
                         {q2[0], q2[1], q2[2], q2[3], q3[0], q3[1], q3[2], q3[3]}};
#pragma unroll
        for (int kc = 0; kc < 2; ++kc) {
            short8 h, lo;
#pragma unroll
            for (int j = 0; j < 8; ++j) {
                float xs = x[kc][j] * SCALE_LOG2E;
                unsigned short hb = f2bf(xs);
                h[j]  = (short)hb;
                lo[j] = (short)f2bf(xs - bf2f(hb));
            }
            qh[kc] = h; ql[kc] = lo;
        }
    }

    floatx4 acc[4];
#pragma unroll
    for (int i = 0; i < 4; ++i) acc[i] = (floatx4){0.f, 0.f, 0.f, 0.f};
    float m_r = -1e30f, l_r = 0.f;

    if (nt > 1) { asm volatile("s_waitcnt vmcnt(6)" ::: "memory"); }
    else        { asm volatile("s_waitcnt vmcnt(0)" ::: "memory"); }
    block_barrier();

    for (int t = 0; t < nt; ++t) {
        const unsigned short* KhiL = (const unsigned short*)lds[t & 1];
        const unsigned short* KloL = KhiL + 4096;
        const unsigned short* VtL  = KhiL + 8192;

        // ---- S^T = K · Q^T (hi/lo split, 3 MFMAs per k-chunk) ----
        floatx4 st[4];
#pragma unroll
        for (int ct = 0; ct < 4; ++ct) {
            floatx4 a = (floatx4){0.f, 0.f, 0.f, 0.f};
#pragma unroll
            for (int kc = 0; kc < 2; ++kc) {
                const int row = ct * 16 + l15;
                const int go = (((kc * 4 + kgi) ^ (row & 7)) << 3);
                const short8 kh = *(const short8*)(KhiL + row * 64 + go);
                const short8 kv = *(const short8*)(KloL + row * 64 + go);
                a = MFMA16(kv, qh[kc], a);
                a = MFMA16(kh, ql[kc], a);
                a = MFMA16(kh, qh[kc], a);
            }
            st[ct] = a;
        }

        // ---- online softmax over t (16 regs + 2 shfl) ----
        float tm = st[0][0];
#pragma unroll
        for (int ct = 0; ct < 4; ++ct)
#pragma unroll
            for (int r = 0; r < 4; ++r) tm = fmaxf(tm, st[ct][r]);
        tm = fmaxf(tm, __shfl_xor(tm, 16));
        tm = fmaxf(tm, __shfl_xor(tm, 32));
        const float nm = fmaxf(m_r, tm);
        const float alpha = __builtin_amdgcn_exp2f(m_r - nm);
        float ps = 0.f;
#pragma unroll
        for (int ct = 0; ct < 4; ++ct)
#pragma unroll
            for (int r = 0; r < 4; ++r) {
                float p = __builtin_amdgcn_exp2f(st[ct][r] - nm);
                st[ct][r] = p;
                ps += p;
            }
        ps += __shfl_xor(ps, 16);
        ps += __shfl_xor(ps, 32);
        l_r = l_r * alpha + ps;
        m_r = nm;
#pragma unroll
        for (int i = 0; i < 4; ++i) acc[i] *= alpha;

        // ---- P^T -> wave-private LDS (packed b64 writes, no barrier) ----
        unsigned short* PTw = &PT[w][0][0];
#pragma unroll
        for (int ct = 0; ct < 4; ++ct) {
            uint2v u = {pkbf(st[ct][0], st[ct][1]), pkbf(st[ct][2], st[ct][3])};
            *(uint2v*)(PTw + l15 * 72 + ct * 16 + kgi * 4) = u;
        }

        // ---- acc^T += V^T · P^T ----
#pragma unroll
        for (int kc = 0; kc < 2; ++kc) {
            const short8 pb = *(const short8*)(PTw + l15 * 72 + kc * 32 + kgi * 8);
#pragma unroll
            for (int db = 0; db < 4; ++db) {
                const int row = db * 16 + l15;
                const int go = (((kc * 4 + kgi) ^ (row & 7)) << 3);
                const short8 va = *(const short8*)(VtL + row * 64 + go);
                acc[db] = MFMA16(va, pb, acc[db]);
            }
        }

        // ---- sync + prefetch tile t+2 (counted vmcnt, never drain in steady state) ----
        if (t + 1 < nt) {
            block_barrier();                       // all waves done reading lds[t&1]
            if (t + 2 < nt) {
                STAGE(t & 1, kv0 + (t + 2) * 64);
                asm volatile("s_waitcnt vmcnt(6)" ::: "memory");   // tile t+1 ready
            } else {
                asm volatile("s_waitcnt vmcnt(0)" ::: "memory");
            }
            block_barrier();                       // lds[(t+1)&1] visible to all
        }
    }

    // ---- epilogue: transpose acc through LDS, write coalesced partials ----
    block_barrier();
    float* Tw = (float*)((char*)lds + w * 4352);   // [16][68] f32 per wave
#pragma unroll
    for (int db = 0; db < 4; ++db)
#pragma unroll
        for (int r = 0; r < 4; ++r)
            Tw[l15 * 68 + db * 16 + kgi * 4 + r] = acc[db][r];
    {
        const int qrow = lane >> 2, gg = lane & 3;
        float* orow = pacc + ((size_t)split * SEQ + qbase + w * 16 + qrow) * 64 + gg * 16;
#pragma unroll
        for (int i = 0; i < 4; ++i)
            *(floatx4*)(orow + i * 4) = *(const floatx4*)&Tw[qrow * 68 + gg * 16 + i * 4];
    }
    if (lane < 16) {
        pm[(size_t)split * SEQ + qbase + w * 16 + lane] = m_r;
        pl[(size_t)split * SEQ + qbase + w * 16 + lane] = l_r;
    }
}

// ---------------- combine kv-split partials -> head[8192][64] ----------------
__global__ void combine_kernel(const float* __restrict__ pacc, const float* __restrict__ pm,
                               const float* __restrict__ pl, float* __restrict__ head, int KS) {
    int idx = blockIdx.x * 256 + threadIdx.x;  // 8192*64
    int qq = idx >> 6, d = idx & 63;
    float M = -1e30f;
    for (int s2 = 0; s2 < KS; ++s2) M = fmaxf(M, pm[(size_t)s2 * SEQ + qq]);
    float L = 0.f, A = 0.f;
    for (int s2 = 0; s2 < KS; ++s2) {
        float wgt = __builtin_amdgcn_exp2f(pm[(size_t)s2 * SEQ + qq] - M);
        L += pl[(size_t)s2 * SEQ + qq] * wgt;
        A += pacc[((size_t)s2 * SEQ + qq) * 64 + d] * wgt;
    }
    head[idx] = A / L;
}

// ---------------- out = head[8192][64] @ w_eff[64][512] (fp32) ----------------
__global__ __launch_bounds__(256) void outproj_kernel(const float* __restrict__ head,
                                                      const float* __restrict__ weff,
                                                      float* __restrict__ out) {
    __shared__ float hlds[16][64];
    const int tid = threadIdx.x;
    const int s0 = blockIdx.x * 16;
    {
        int sl = tid >> 4, dc = (tid & 15) * 4;
        *(floatx4*)&hlds[sl][dc] = *(const floatx4*)&head[(size_t)(s0 + sl) * 64 + dc];
    }
    __syncthreads();
    const int j0 = tid * 2;
    float a0[16], a1[16];
#pragma unroll
    for (int s = 0; s < 16; ++s) { a0[s] = 0.f; a1[s] = 0.f; }
    for (int d4 = 0; d4 < 16; ++d4) {
        floatx2 wv[4];
#pragma unroll
        for (int dd = 0; dd < 4; ++dd)
            wv[dd] = *(const floatx2*)&weff[(size_t)(d4 * 4 + dd) * 512 + j0];
#pragma unroll
        for (int s = 0; s < 16; ++s) {
            floatx4 h = *(const floatx4*)&hlds[s][d4 * 4];
#pragma unroll
            for (int dd = 0; dd < 4; ++dd) {
                a0[s] += h[dd] * wv[dd][0];
                a1[s] += h[dd] * wv[dd][1];
            }
        }
    }
#pragma unroll
    for (int s = 0; s < 16; ++s) {
        floatx2 o = {a0[s], a1[s]};
        *(floatx2*)&out[(size_t)(s0 + s) * 512 + j0] = o;
    }
}

extern "C" void kernel_launch(void* const* d_in, const int* in_sizes, int n_in,
                              void* d_out, int out_size, void* d_ws, size_t ws_size,
                              hipStream_t stream) {
    const float* q   = (const float*)d_in[0];
    const float* k   = (const float*)d_in[1];
    const float* v   = (const float*)d_in[2];
    const float* w_o = (const float*)d_in[3];
    float* out = (float*)d_out;

    const size_t weff_sz = 64 * 512 * sizeof(float);
    const size_t head_sz = (size_t)SEQ * 64 * sizeof(float);
    const size_t bf_sz   = (size_t)SEQ * 64 * sizeof(unsigned short);  // 1 MB each
    auto need = [&](int ks) {
        return weff_sz + head_sz + 3 * bf_sz
               + (size_t)ks * SEQ * 64 * sizeof(float)
               + 2 * (size_t)ks * SEQ * sizeof(float);
    };
    int KS = 1;
    if (ws_size >= need(4)) KS = 4;
    else if (ws_size >= need(2)) KS = 2;

    char* p = (char*)d_ws;
    float* weff = (float*)p;  p += weff_sz;
    float* pacc = (float*)p;  p += (size_t)KS * SEQ * 64 * sizeof(float);
    float* pm   = (float*)p;  p += (size_t)KS * SEQ * sizeof(float);
    float* pl   = (float*)p;  p += (size_t)KS * SEQ * sizeof(float);
    float* head = (float*)p;  p += head_sz;
    unsigned short* khi = (unsigned short*)p;  p += bf_sz;
    unsigned short* klo = (unsigned short*)p;  p += bf_sz;
    unsigned short* vt  = (unsigned short*)p;

    weff_kernel<<<dim3(128), dim3(256), 0, stream>>>(w_o, weff);
    khilo_kernel<<<dim3(SEQ * 64 / 8 / 256), dim3(256), 0, stream>>>(k, khi, klo);
    vtrans_kernel<<<dim3(SEQ / 64), dim3(256), 0, stream>>>(v, vt);
    flash_kernel<<<dim3(SEQ / 64, KS), dim3(256), 0, stream>>>(q, khi, klo, vt, pacc, pm, pl, SEQ / KS);
    combine_kernel<<<dim3((SEQ * 64) / 256), dim3(256), 0, stream>>>(pacc, pm, pl, head, KS);
    outproj_kernel<<<dim3(SEQ / 16), dim3(256), 0, stream>>>(head, weff, out);
}

// Round 5
// 120.699 us; speedup vs baseline: 1.7052x; 1.1867x over previous
//
#include <hip/hip_runtime.h>
#include <hip/hip_bf16.h>

typedef _Float16 half8 __attribute__((ext_vector_type(8)));
typedef __fp16 fp16x2 __attribute__((ext_vector_type(2)));
typedef __attribute__((ext_vector_type(4))) float floatx4;
typedef __attribute__((ext_vector_type(2))) float floatx2;
typedef __attribute__((ext_vector_type(2))) unsigned int uint2v;

#define MFMAH(a, b, c) __builtin_amdgcn_mfma_f32_16x16x32_f16((a), (b), (c), 0, 0, 0)

#define SEQ 8192
#define SCALE_LOG2E 0.18033688011112042f  /* (1/sqrt(64)) * log2(e) */

__device__ __forceinline__ unsigned pkh(float a, float b) {
    union { fp16x2 h; unsigned u; } cv;
    cv.h = __builtin_amdgcn_cvt_pkrtz(a, b);
    return cv.u;
}
__device__ __forceinline__ void gload16(const void* gptr, void* lptr) {
    __builtin_amdgcn_global_load_lds(
        (const __attribute__((address_space(1))) void*)gptr,
        (__attribute__((address_space(3))) void*)lptr, 16, 0, 0);
}
__device__ __forceinline__ void block_barrier() {
    asm volatile("" ::: "memory");
    __builtin_amdgcn_s_barrier();
    asm volatile("" ::: "memory");
}

// ---------------- fused prep: K->fp16 | V->Vt fp16 | weff ----------------
// blocks 0..255: K convert; 256..383: V transpose; 384..511: weff reduce.
__global__ __launch_bounds__(256) void prep_kernel(
        const float* __restrict__ kg, const float* __restrict__ vg,
        const float* __restrict__ w_o, _Float16* __restrict__ kf,
        _Float16* __restrict__ vt, float* __restrict__ weff) {
    const int bid = blockIdx.x, tid = threadIdx.x;
    if (bid < 256) {                       // K: fp32 -> fp16, row-major [SEQ][64]
        int e = (bid * 256 + tid) * 8;
        floatx4 a = *(const floatx4*)(kg + e);
        floatx4 b = *(const floatx4*)(kg + e + 4);
        half8 h;
        h[0] = (_Float16)a[0]; h[1] = (_Float16)a[1]; h[2] = (_Float16)a[2]; h[3] = (_Float16)a[3];
        h[4] = (_Float16)b[0]; h[5] = (_Float16)b[1]; h[6] = (_Float16)b[2]; h[7] = (_Float16)b[3];
        *(half8*)(kf + e) = h;
    } else if (bid < 384) {                // V: [SEQ][64] f32 -> Vt [64][SEQ] fp16
        __shared__ _Float16 T[64][72];
        const int t0 = (bid - 256) * 64;
        {
            int r = tid >> 2, cs = (tid & 3) * 16;
            const float* vp = vg + (size_t)(t0 + r) * 64 + cs;
            half8 h0, h1;
#pragma unroll
            for (int j = 0; j < 8; ++j) { h0[j] = (_Float16)vp[j]; h1[j] = (_Float16)vp[8 + j]; }
            *(half8*)&T[r][cs] = h0;
            *(half8*)&T[r][cs + 8] = h1;
        }
        __syncthreads();
        {
            int d = tid >> 2, ts = (tid & 3) * 16;
            half8 o0, o1;
#pragma unroll
            for (int j = 0; j < 8; ++j) { o0[j] = T[ts + j][d]; o1[j] = T[ts + 8 + j][d]; }
            *(half8*)(vt + (size_t)d * SEQ + t0 + ts) = o0;
            *(half8*)(vt + (size_t)d * SEQ + t0 + ts + 8) = o1;
        }
    } else {                               // weff[d][j] = sum_h w_o[h*64+d][j]
        int idx = (bid - 384) * 256 + tid;  // 64*512
        int d = idx >> 9, j = idx & 511;
        float s = 0.f;
#pragma unroll
        for (int h = 0; h < 8; ++h) s += w_o[((h * 64 + d) << 9) + j];
        weff[idx] = s;
    }
}

// ---------------- flash attention: fp16, 32q/wave, BQ=128, KVB=64 ----------------
// Grid: (SEQ/128, KS). Block 256 = 4 waves; wave w owns q cols [qbase+w*32, +32).
// LDS/buf: K[64][64]h (8K) + Vt[64][64]h (8K), 16B-granule XOR-swizzled via
// inverse-swizzled global SOURCE (LDS linear, rule 21). PT = per-wave/qf P^T.
__global__ __launch_bounds__(256, 2) void flash_kernel(
        const float* __restrict__ qg, const _Float16* __restrict__ kf,
        const _Float16* __restrict__ vt, float* __restrict__ pacc,
        float* __restrict__ pm, float* __restrict__ pl, int kvlen) {
    __shared__ __align__(16) char smem[51200];   // 2x16384 stage | 18432 PT
    _Float16* PTbase = (_Float16*)(smem + 32768);

    const int tid  = threadIdx.x;
    const int lane = tid & 63;
    const int w    = tid >> 6;
    const int l15  = lane & 15;
    const int kgi  = lane >> 4;
    const int qbase = blockIdx.x * 128;
    const int split = blockIdx.y;
    const int kv0   = split * kvlen;
    const int nt    = kvlen >> 6;

    // staging: thread covers row r0 / r0+32, 16B granule, source-swizzled
    const int r0 = tid >> 3;                       // 0..31
    const int g8 = (((tid & 7) ^ (r0 & 7)) << 3);  // granule*8 elems (halfs)

    auto STAGE = [&](int bsel, int kvb) {
        char* b = smem + bsel * 16384;
        const size_t ko = (size_t)(kvb + r0) * 64 + g8;
        const size_t vo = (size_t)r0 * SEQ + kvb + g8;
        gload16(kf + ko,                    b + tid * 16);
        gload16(kf + ko + 32 * 64,          b + 4096  + tid * 16);
        gload16(vt + vo,                    b + 8192  + tid * 16);
        gload16(vt + vo + (size_t)32 * SEQ, b + 12288 + tid * 16);
    };

    // ---- Q loads, prefetch tiles 0,1, convert Q to fp16 (scale folded) ----
    const float* qp = qg + (size_t)(qbase + w * 32 + l15) * 64 + kgi * 8;
    floatx4 qv[2][2][2];
#pragma unroll
    for (int qf = 0; qf < 2; ++qf)
#pragma unroll
        for (int kc = 0; kc < 2; ++kc) {
            qv[qf][kc][0] = *(const floatx4*)(qp + qf * 16 * 64 + kc * 32);
            qv[qf][kc][1] = *(const floatx4*)(qp + qf * 16 * 64 + kc * 32 + 4);
        }

    STAGE(0, kv0);
    STAGE(1, kv0 + 64);

    half8 qh[2][2];
#pragma unroll
    for (int qf = 0; qf < 2; ++qf)
#pragma unroll
        for (int kc = 0; kc < 2; ++kc) {
            half8 h;
#pragma unroll
            for (int i = 0; i < 4; ++i) {
                h[i]     = (_Float16)(qv[qf][kc][0][i] * SCALE_LOG2E);
                h[i + 4] = (_Float16)(qv[qf][kc][1][i] * SCALE_LOG2E);
            }
            qh[qf][kc] = h;
        }

    floatx4 acc[2][4];
#pragma unroll
    for (int qf = 0; qf < 2; ++qf)
#pragma unroll
        for (int i = 0; i < 4; ++i) acc[qf][i] = (floatx4){0.f, 0.f, 0.f, 0.f};
    float m_r[2] = {-1e30f, -1e30f}, l_r[2] = {0.f, 0.f};

    asm volatile("s_waitcnt vmcnt(4)" ::: "memory");   // tile 0 staged
    block_barrier();

    for (int t = 0; t < nt; ++t) {
        const _Float16* KL = (const _Float16*)(smem + (t & 1) * 16384);
        const _Float16* VL = KL + 4096;

        // ---- S^T[64t][32q] = K · Q^T (1 fp16 MFMA per k-chunk, K read shared by qf) ----
        floatx4 st[2][4];
#pragma unroll
        for (int qf = 0; qf < 2; ++qf)
#pragma unroll
            for (int ct = 0; ct < 4; ++ct) st[qf][ct] = (floatx4){0.f, 0.f, 0.f, 0.f};
#pragma unroll
        for (int ct = 0; ct < 4; ++ct) {
            const int row = ct * 16 + l15;
#pragma unroll
            for (int kc = 0; kc < 2; ++kc) {
                const int go = (((kc * 4 + kgi) ^ (row & 7)) << 3);
                const half8 kh = *(const half8*)(KL + row * 64 + go);
                st[0][ct] = MFMAH(kh, qh[0][kc], st[0][ct]);
                st[1][ct] = MFMAH(kh, qh[1][kc], st[1][ct]);
            }
        }

        // ---- online softmax per qf (defer-max THR=8) + pack P^T to LDS ----
#pragma unroll
        for (int qf = 0; qf < 2; ++qf) {
            float tm = st[qf][0][0];
#pragma unroll
            for (int ct = 0; ct < 4; ++ct)
#pragma unroll
                for (int r = 0; r < 4; ++r) tm = fmaxf(tm, st[qf][ct][r]);
            tm = fmaxf(tm, __shfl_xor(tm, 16));
            tm = fmaxf(tm, __shfl_xor(tm, 32));
            if (!__all(tm - m_r[qf] <= 8.0f)) {
                const float nm = fmaxf(m_r[qf], tm);
                const float alpha = __builtin_amdgcn_exp2f(m_r[qf] - nm);
                l_r[qf] *= alpha;
#pragma unroll
                for (int db = 0; db < 4; ++db) acc[qf][db] *= alpha;
                m_r[qf] = nm;
            }
            const float nm = m_r[qf];
            float ps = 0.f;
#pragma unroll
            for (int ct = 0; ct < 4; ++ct)
#pragma unroll
                for (int r = 0; r < 4; ++r) {
                    float p = __builtin_amdgcn_exp2f(st[qf][ct][r] - nm);
                    st[qf][ct][r] = p;
                    ps += p;
                }
            ps += __shfl_xor(ps, 16);
            ps += __shfl_xor(ps, 32);
            l_r[qf] += ps;

            _Float16* PTw = PTbase + (w * 2 + qf) * (16 * 72);
#pragma unroll
            for (int ct = 0; ct < 4; ++ct) {
                uint2v u = {pkh(st[qf][ct][0], st[qf][ct][1]),
                            pkh(st[qf][ct][2], st[qf][ct][3])};
                *(uint2v*)(PTw + l15 * 72 + ct * 16 + kgi * 4) = u;
            }
        }

        // ---- acc^T += V^T · P^T (V read shared by qf) ----
        {
            _Float16* PT0 = PTbase + (w * 2 + 0) * (16 * 72);
            _Float16* PT1 = PTbase + (w * 2 + 1) * (16 * 72);
#pragma unroll
            for (int kc = 0; kc < 2; ++kc) {
                const half8 pb0 = *(const half8*)(PT0 + l15 * 72 + kc * 32 + kgi * 8);
                const half8 pb1 = *(const half8*)(PT1 + l15 * 72 + kc * 32 + kgi * 8);
#pragma unroll
                for (int db = 0; db < 4; ++db) {
                    const int row = db * 16 + l15;
                    const int go = (((kc * 4 + kgi) ^ (row & 7)) << 3);
                    const half8 va = *(const half8*)(VL + row * 64 + go);
                    acc[0][db] = MFMAH(va, pb0, acc[0][db]);
                    acc[1][db] = MFMAH(va, pb1, acc[1][db]);
                }
            }
        }

        // ---- barrier + prefetch t+2 with counted vmcnt ----
        if (t + 1 < nt) {
            block_barrier();
            if (t + 2 < nt) {
                STAGE(t & 1, kv0 + (t + 2) * 64);
                asm volatile("s_waitcnt vmcnt(4)" ::: "memory");   // t+1 ready
            } else {
                asm volatile("s_waitcnt vmcnt(0)" ::: "memory");
            }
            block_barrier();
        }
    }

    // ---- epilogue: transpose acc via LDS, coalesced partial writes ----
    block_barrier();   // all waves done with stage buffers
    float* Tw = (float*)(smem + w * 4352);   // [16][68] f32, per wave (reused per qf)
#pragma unroll
    for (int qf = 0; qf < 2; ++qf) {
#pragma unroll
        for (int db = 0; db < 4; ++db)
#pragma unroll
            for (int r = 0; r < 4; ++r)
                Tw[l15 * 68 + db * 16 + kgi * 4 + r] = acc[qf][db][r];
        {
            const int qrow = lane >> 2, gg = lane & 3;
            float* orow = pacc + ((size_t)split * SEQ + qbase + w * 32 + qf * 16 + qrow) * 64 + gg * 16;
#pragma unroll
            for (int i = 0; i < 4; ++i)
                *(floatx4*)(orow + i * 4) = *(const floatx4*)&Tw[qrow * 68 + gg * 16 + i * 4];
        }
        if (lane < 16) {
            pm[(size_t)split * SEQ + qbase + w * 32 + qf * 16 + lane] = m_r[qf];
            pl[(size_t)split * SEQ + qbase + w * 32 + qf * 16 + lane] = l_r[qf];
        }
        __builtin_amdgcn_s_barrier();   // Tw reuse between qf iterations (wave-sync ok)
    }
}

// ---------------- fused combine + outproj ----------------
// Block handles 16 s-rows: merge KS split partials into head[16][64] (LDS),
// then out[16][512] = head @ weff.
__global__ __launch_bounds__(256) void combineproj_kernel(
        const float* __restrict__ pacc, const float* __restrict__ pm,
        const float* __restrict__ pl, const float* __restrict__ weff,
        float* __restrict__ out, int KS) {
    __shared__ float hlds[16][64];
    const int tid = threadIdx.x;
    const int s0 = blockIdx.x * 16;
    {
        const int row = tid >> 4, d0 = (tid & 15) * 4;
        const int qq = s0 + row;
        float M = -1e30f;
        for (int s2 = 0; s2 < KS; ++s2) M = fmaxf(M, pm[(size_t)s2 * SEQ + qq]);
        floatx4 A = (floatx4){0.f, 0.f, 0.f, 0.f};
        float L = 0.f;
        for (int s2 = 0; s2 < KS; ++s2) {
            const float wgt = __builtin_amdgcn_exp2f(pm[(size_t)s2 * SEQ + qq] - M);
            L += pl[(size_t)s2 * SEQ + qq] * wgt;
            floatx4 pa = *(const floatx4*)&pacc[((size_t)s2 * SEQ + qq) * 64 + d0];
            A += pa * wgt;
        }
        const float inv = 1.0f / L;
        A *= inv;
        *(floatx4*)&hlds[row][d0] = A;
    }
    __syncthreads();
    const int j0 = tid * 2;
    float a0[16], a1[16];
#pragma unroll
    for (int s = 0; s < 16; ++s) { a0[s] = 0.f; a1[s] = 0.f; }
    for (int d4 = 0; d4 < 16; ++d4) {
        floatx2 wv[4];
#pragma unroll
        for (int dd = 0; dd < 4; ++dd)
            wv[dd] = *(const floatx2*)&weff[(size_t)(d4 * 4 + dd) * 512 + j0];
#pragma unroll
        for (int s = 0; s < 16; ++s) {
            floatx4 h = *(const floatx4*)&hlds[s][d4 * 4];
#pragma unroll
            for (int dd = 0; dd < 4; ++dd) {
                a0[s] += h[dd] * wv[dd][0];
                a1[s] += h[dd] * wv[dd][1];
            }
        }
    }
#pragma unroll
    for (int s = 0; s < 16; ++s) {
        floatx2 o = {a0[s], a1[s]};
        *(floatx2*)&out[(size_t)(s0 + s) * 512 + j0] = o;
    }
}

extern "C" void kernel_launch(void* const* d_in, const int* in_sizes, int n_in,
                              void* d_out, int out_size, void* d_ws, size_t ws_size,
                              hipStream_t stream) {
    const float* q   = (const float*)d_in[0];
    const float* k   = (const float*)d_in[1];
    const float* v   = (const float*)d_in[2];
    const float* w_o = (const float*)d_in[3];
    float* out = (float*)d_out;

    const size_t weff_sz = 64 * 512 * sizeof(float);
    const size_t h_sz    = (size_t)SEQ * 64 * sizeof(_Float16);   // 1 MB
    auto need = [&](int ks) {
        return weff_sz + 2 * h_sz
               + (size_t)ks * SEQ * 64 * sizeof(float)
               + 2 * (size_t)ks * SEQ * sizeof(float);
    };
    int KS = 1;
    if (ws_size >= need(8)) KS = 8;
    else if (ws_size >= need(4)) KS = 4;
    else if (ws_size >= need(2)) KS = 2;

    char* p = (char*)d_ws;
    float* weff = (float*)p;  p += weff_sz;
    float* pacc = (float*)p;  p += (size_t)KS * SEQ * 64 * sizeof(float);
    float* pm   = (float*)p;  p += (size_t)KS * SEQ * sizeof(float);
    float* pl   = (float*)p;  p += (size_t)KS * SEQ * sizeof(float);
    _Float16* kf = (_Float16*)p;  p += h_sz;
    _Float16* vt = (_Float16*)p;

    prep_kernel<<<dim3(512), dim3(256), 0, stream>>>(k, v, w_o, kf, vt, weff);
    flash_kernel<<<dim3(SEQ / 128, KS), dim3(256), 0, stream>>>(q, kf, vt, pacc, pm, pl, SEQ / KS);
    combineproj_kernel<<<dim3(SEQ / 16), dim3(256), 0, stream>>>(pacc, pm, pl, weff, out, KS);
}